// Round 1
// baseline (381.474 us; speedup 1.0000x reference)
//
#include <hip/hip_runtime.h>
#include <math.h>

#define HH 64
#define WW 64
#define KS 5
#define CPP 8
#define NPOS 48
#define CHAN (NPOS * CPP)   // 384
#define NBATCH 32

// Fused DisplaceChannel: integer shift + separable 5x5 Gaussian depthwise conv.
// Block = (batch, position): 256 threads = 8 channels x (8 x-segments x 4 y-strips).
// Each thread: 8 consecutive x cols x 16 rows, vertical pass via 5-row register
// sliding window of horizontally-filtered rows. No LDS; L1 absorbs halo re-reads.
__global__ __launch_bounds__(256)
void displace_sep_kernel(const float* __restrict__ x,
                         const float* __restrict__ off,
                         float* __restrict__ out)
{
    const int bp = blockIdx.x;            // 0 .. NBATCH*NPOS-1
    const int p  = bp % NPOS;
    const int b  = bp / NPOS;

    const int t  = threadIdx.x;
    const int tx = t & 7;                 // 8-wide x segment
    const int ty = (t >> 3) & 3;          // 16-row y strip
    const int cc = t >> 5;                // channel within position group

    const int x0 = tx * 8;
    const int y0 = ty * 16;

    const size_t plane = ((size_t)b * CHAN + (size_t)p * CPP + (size_t)cc) * (HH * WW);
    const float* __restrict__ src = x + plane;
    float* __restrict__ dst = out + plane;

    // --- per-position offset -> integer shift + separable Gaussian weights ---
    const float offx = off[2 * p + 0];
    const float offy = off[2 * p + 1];
    const float rx = rintf(offx), ry = rintf(offy);
    const int   dx = (int)rx,     dy = (int)ry;
    const float subx = offx - rx, suby = offy - ry;

    float wx[KS], wy[KS];
    float sumx = 0.f, sumy = 0.f;
    #pragma unroll
    for (int k = 0; k < KS; ++k) {
        const float ax = (float)(k - 2) + subx;
        const float ay = (float)(k - 2) + suby;
        wx[k] = __expf(-2.0f * ax * ax);   // 1/(2*sigma^2) = 2, sigma = 0.5
        wy[k] = __expf(-2.0f * ay * ay);
        sumx += wx[k];
        sumy += wy[k];
    }
    const float inv = 1.0f / (sumx * sumy);
    #pragma unroll
    for (int k = 0; k < KS; ++k) wx[k] *= inv;   // fold full 2D normalization into wx

    // --- horizontal window: j=0..11 <-> displaced col xx = x0-2+j, source col sx=xx-dx
    int   saddr[12];
    float smask[12];
    #pragma unroll
    for (int j = 0; j < 12; ++j) {
        const int xx = x0 - 2 + j;
        const int sx = xx - dx;
        const bool ok = ((unsigned)xx < (unsigned)WW) && ((unsigned)sx < (unsigned)WW);
        saddr[j] = ok ? sx : 0;
        smask[j] = ok ? 1.0f : 0.0f;
    }

    float hb[5][8];   // sliding window of horizontally-filtered rows, keyed by yy

    #pragma unroll
    for (int i = 0; i < 20; ++i) {
        // produce H row for displaced row yy = y0-2+i into slot i%5
        const int yy = y0 - 2 + i;
        const int sy = yy - dy;
        const bool rowok = ((unsigned)yy < (unsigned)HH) && ((unsigned)sy < (unsigned)HH);
        float (&h)[8] = hb[i % 5];
        if (rowok) {
            const float* __restrict__ row = src + sy * WW;
            float s[12];
            #pragma unroll
            for (int j = 0; j < 12; ++j)
                s[j] = row[saddr[j]] * smask[j];
            #pragma unroll
            for (int j = 0; j < 8; ++j) {
                float a = wx[0] * s[j];
                a = fmaf(wx[1], s[j + 1], a);
                a = fmaf(wx[2], s[j + 2], a);
                a = fmaf(wx[3], s[j + 3], a);
                a = fmaf(wx[4], s[j + 4], a);
                h[j] = a;
            }
        } else {
            #pragma unroll
            for (int j = 0; j < 8; ++j) h[j] = 0.0f;
        }

        // once rows y-2..y+2 are resident, emit output row y = y0 + i - 4
        if (i >= 4) {
            const int y = y0 + i - 4;
            float acc[8];
            #pragma unroll
            for (int j = 0; j < 8; ++j) acc[j] = 0.0f;
            #pragma unroll
            for (int ky = 0; ky < KS; ++ky) {
                const float w = wy[ky];
                float (&hr)[8] = hb[(i - 4 + ky) % 5];
                #pragma unroll
                for (int j = 0; j < 8; ++j)
                    acc[j] = fmaf(w, hr[j], acc[j]);
            }
            float4* o4 = (float4*)(dst + (size_t)y * WW + x0);
            o4[0] = make_float4(acc[0], acc[1], acc[2], acc[3]);
            o4[1] = make_float4(acc[4], acc[5], acc[6], acc[7]);
        }
    }
}

extern "C" void kernel_launch(void* const* d_in, const int* in_sizes, int n_in,
                              void* d_out, int out_size, void* d_ws, size_t ws_size,
                              hipStream_t stream) {
    const float* x   = (const float*)d_in[0];
    const float* off = (const float*)d_in[1];
    float* out = (float*)d_out;

    const int blocks = NBATCH * NPOS;   // 1536
    displace_sep_kernel<<<blocks, 256, 0, stream>>>(x, off, out);
}

// Round 2
// 349.808 us; speedup vs baseline: 1.0905x; 1.0905x over previous
//
#include <hip/hip_runtime.h>
#include <math.h>

#define HH 64
#define WW 64
#define KS 5
#define CPP 8
#define NPOS 48
#define CHAN (NPOS * CPP)   // 384
#define NBATCH 32
#define STRIP 32            // rows per wave

// One wave per (plane, 32-row strip). Lane = x column (W=64 = wave width).
// Load of displaced row is a single coalesced 256B global_load_dword per row
// (shift dx is wave-uniform). Horizontal 5-tap Gaussian via 4 __shfl with
// per-lane masked weights (conv zero-pad + normalization folded into wxm).
// Vertical 5-tap via 5-register sliding window. No LDS.
__global__ __launch_bounds__(256)
void displace_wave_kernel(const float* __restrict__ x,
                          const float* __restrict__ off,
                          float* __restrict__ out)
{
    const int t    = threadIdx.x;
    const int lane = t & 63;
    const int gw   = blockIdx.x * 4 + (t >> 6);   // global wave id
    const int half = gw & 1;                      // which 32-row strip
    const int plane = gw >> 1;                    // b*CHAN + p*CPP + cc
    const int p    = (plane % CHAN) / CPP;        // position index

    const float* __restrict__ src = x   + (size_t)plane * (HH * WW);
    float*       __restrict__ dst = out + (size_t)plane * (HH * WW);

    // --- per-position offset -> integer shift + separable Gaussian weights ---
    const float offx = off[2 * p + 0];
    const float offy = off[2 * p + 1];
    const float rxf = rintf(offx), ryf = rintf(offy);
    const int   dx = (int)rxf,     dy = (int)ryf;
    const float subx = offx - rxf, suby = offy - ryf;

    float wxr[KS], wy[KS];
    float sumx = 0.f, sumy = 0.f;
    #pragma unroll
    for (int k = 0; k < KS; ++k) {
        const float ax = (float)(k - 2) + subx;
        const float ay = (float)(k - 2) + suby;
        wxr[k] = __expf(-2.0f * ax * ax);   // 1/(2*sigma^2) = 2 (sigma = 0.5)
        wy[k]  = __expf(-2.0f * ay * ay);
        sumx += wxr[k];
        sumy += wy[k];
    }
    const float inv = 1.0f / (sumx * sumy);

    // horizontal weights, masked per lane: tap k reads lane+k-2; zero if that
    // displaced column is outside [0, W) (conv zero padding). Fold full 2D
    // normalization in here.
    float wxm[KS];
    #pragma unroll
    for (int k = 0; k < KS; ++k) {
        const int sl = lane + (k - 2);
        wxm[k] = ((unsigned)sl < (unsigned)WW) ? wxr[k] * inv : 0.0f;
    }

    // per-lane source column for displaced row D[xx]=src[..][xx-dx] (invariant)
    const int   sx  = lane - dx;
    const float mx  = ((unsigned)sx < (unsigned)WW) ? 1.0f : 0.0f;
    const int   sxc = min(max(sx, 0), WW - 1);

    const int y0 = half * STRIP;
    float hb[5];   // sliding window of horizontally-filtered rows

    #pragma unroll
    for (int i = 0; i < STRIP + 4; ++i) {
        const int yy = y0 - 2 + i;        // displaced row index
        const int sy = yy - dy;           // source row index
        float h = 0.0f;
        if (((unsigned)yy < (unsigned)HH) & ((unsigned)sy < (unsigned)HH)) {
            const float v   = src[sy * WW + sxc] * mx;
            const float sm2 = __shfl(v, (lane + 62) & 63);
            const float sm1 = __shfl(v, (lane + 63) & 63);
            const float sp1 = __shfl(v, (lane + 1)  & 63);
            const float sp2 = __shfl(v, (lane + 2)  & 63);
            h = wxm[0] * sm2;
            h = fmaf(wxm[1], sm1, h);
            h = fmaf(wxm[2], v,   h);
            h = fmaf(wxm[3], sp1, h);
            h = fmaf(wxm[4], sp2, h);
        }
        hb[i % 5] = h;

        if (i >= 4) {
            const int y = y0 + i - 4;
            float a = wy[0] * hb[(i - 4) % 5];
            a = fmaf(wy[1], hb[(i - 3) % 5], a);
            a = fmaf(wy[2], hb[(i - 2) % 5], a);
            a = fmaf(wy[3], hb[(i - 1) % 5], a);
            a = fmaf(wy[4], hb[(i - 0) % 5], a);
            dst[y * WW + lane] = a;
        }
    }
}

extern "C" void kernel_launch(void* const* d_in, const int* in_sizes, int n_in,
                              void* d_out, int out_size, void* d_ws, size_t ws_size,
                              hipStream_t stream) {
    const float* x   = (const float*)d_in[0];
    const float* off = (const float*)d_in[1];
    float* out = (float*)d_out;

    // waves = planes * 2 strips = 32*384*2 = 24576; 4 waves per 256-thread block
    const int blocks = NBATCH * CHAN * 2 / 4;   // 6144
    displace_wave_kernel<<<blocks, 256, 0, stream>>>(x, off, out);
}

// Round 3
// 319.187 us; speedup vs baseline: 1.1951x; 1.0959x over previous
//
#include <hip/hip_runtime.h>
#include <math.h>

#define HH 64
#define WW 64
#define KS 5
#define CPP 8
#define NPOS 48
#define CHAN (NPOS * CPP)   // 384
#define NBATCH 32

// DPP wave shifts: full-rate VALU cross-lane, no LDS pipe, no lgkmcnt.
// wave_shr:1 (0x138): lane i <- lane i-1.  wave_shl:1 (0x130): lane i <- lane i+1.
__device__ __forceinline__ float dpp_shr1(float v) {
    return __int_as_float(__builtin_amdgcn_mov_dpp(__float_as_int(v), 0x138, 0xF, 0xF, true));
}
__device__ __forceinline__ float dpp_shl1(float v) {
    return __int_as_float(__builtin_amdgcn_mov_dpp(__float_as_int(v), 0x130, 0xF, 0xF, true));
}

// One wave per 64x64 plane. Lane = x column. Per displaced row: one coalesced
// global_load_dword (shift dx is wave-uniform, folded into per-lane source col),
// horizontal 5-tap via 4 chained DPP wave shifts + masked weights (conv zero-pad
// + source-validity + normalization folded into wxm / mx), vertical 5-tap via
// 5-register sliding window. Plane index readfirstlane'd -> scalar base addressing.
__global__ __launch_bounds__(256)
void displace_dpp_kernel(const float* __restrict__ x,
                         const float* __restrict__ off,
                         float* __restrict__ out)
{
    const int t    = threadIdx.x;
    const int lane = t & 63;
    const int plane = __builtin_amdgcn_readfirstlane(blockIdx.x * 4 + (t >> 6));
    const int p = (plane % CHAN) / CPP;          // position index (wave-uniform)

    const float* __restrict__ src = x   + (size_t)plane * (HH * WW);
    float*       __restrict__ dst = out + (size_t)plane * (HH * WW);

    // --- offset -> integer shift + separable Gaussian weights (sigma=0.5) ---
    const float offx = off[2 * p + 0];
    const float offy = off[2 * p + 1];
    const float rxf = rintf(offx), ryf = rintf(offy);
    const int   dx = (int)rxf,     dy = (int)ryf;
    const float subx = offx - rxf, suby = offy - ryf;

    float wxr[KS], wy[KS];
    float sumx = 0.f, sumy = 0.f;
    #pragma unroll
    for (int k = 0; k < KS; ++k) {
        const float ax = (float)(k - 2) + subx;
        const float ay = (float)(k - 2) + suby;
        wxr[k] = __expf(-2.0f * ax * ax);
        wy[k]  = __expf(-2.0f * ay * ay);
        sumx += wxr[k];
        sumy += wy[k];
    }
    const float inv = 1.0f / (sumx * sumy);

    // tap k reads displaced column lane+k-2: zero if outside [0,W) (conv pad).
    // Fold full 2D normalization in. (Neighbor's own source-validity is folded
    // into that neighbor's loaded value via mx.)
    float wxm[KS];
    #pragma unroll
    for (int k = 0; k < KS; ++k) {
        const int sl = lane + (k - 2);
        wxm[k] = ((unsigned)sl < (unsigned)WW) ? wxr[k] * inv : 0.0f;
    }

    // per-lane source column for displaced value D[lane] = src[.][lane-dx]
    const int   sx  = lane - dx;
    const float mx  = ((unsigned)sx < (unsigned)WW) ? 1.0f : 0.0f;
    const int   sxc = min(max(sx, 0), WW - 1);

    float hb[5];   // sliding window of horizontally-filtered rows

    #pragma unroll
    for (int i = 0; i < HH + 4; ++i) {
        const int  yy = i - 2;            // displaced row
        const int  sy = yy - dy;          // source row
        const bool rowok = (((unsigned)yy < (unsigned)HH) & ((unsigned)sy < (unsigned)HH));
        const int  syc = min(max(sy, 0), HH - 1);

        const float v   = src[syc * WW + sxc] * mx;   // D[lane] (masked)
        const float sm1 = dpp_shr1(v);                // D[lane-1]
        const float sm2 = dpp_shr1(sm1);              // D[lane-2]
        const float sp1 = dpp_shl1(v);                // D[lane+1]
        const float sp2 = dpp_shl1(sp1);              // D[lane+2]

        float h = wxm[0] * sm2;
        h = fmaf(wxm[1], sm1, h);
        h = fmaf(wxm[2], v,   h);
        h = fmaf(wxm[3], sp1, h);
        h = fmaf(wxm[4], sp2, h);
        hb[i % 5] = rowok ? h : 0.0f;

        if (i >= 4) {
            const int y = i - 4;
            float a = wy[0] * hb[(i - 4) % 5];
            a = fmaf(wy[1], hb[(i - 3) % 5], a);
            a = fmaf(wy[2], hb[(i - 2) % 5], a);
            a = fmaf(wy[3], hb[(i - 1) % 5], a);
            a = fmaf(wy[4], hb[(i - 0) % 5], a);
            dst[y * WW + lane] = a;
        }
    }
}

extern "C" void kernel_launch(void* const* d_in, const int* in_sizes, int n_in,
                              void* d_out, int out_size, void* d_ws, size_t ws_size,
                              hipStream_t stream) {
    const float* x   = (const float*)d_in[0];
    const float* off = (const float*)d_in[1];
    float* out = (float*)d_out;

    // one wave per plane; 4 waves (planes) per 256-thread block
    const int blocks = NBATCH * CHAN / 4;   // 3072
    displace_dpp_kernel<<<blocks, 256, 0, stream>>>(x, off, out);
}